// Round 6
// baseline (173.581 us; speedup 1.0000x reference)
//
#include <hip/hip_runtime.h>
#include <cstdint>
#include <cstddef>

#define N_ANCH 25200
#define NB0 19200
#define NB1 24000
#define TOPK_N 4096
#define CONF_T 0.001
#define NMS_T 0.6
#define IMGS 640.0
#define NBINS 8192       // fp32 bits >> 17 (exponent + 6 mantissa bits)

#define K1_B 512
#define K1_G 197         // ceil(25200*4 / 512)
#define K2_B 1024
#define K2_G 197         // ceil(25200 / 128) i-chunks of 128
#define K2_JS 8          // j-slices within a block (tid >> 7)
#define NCLS 80
#define NMAXB 256        // bit-matrix NMS path cap (fallback above)

typedef unsigned long long u64;
typedef unsigned int u32;

struct WS {
  alignas(64) double sc[N_ANCH];       // masked score (sc or -1.0), fp64
  alignas(64) double box[N_ANCH][4];   // clipped normalized boxes, fp64
  alignas(64) int    cls[N_ANCH];
  alignas(64) u64    skey[N_ANCH];     // (sortable fp32 bits << 32) | (~anchor id)
  alignas(64) double tbox[TOPK_N][4];
  alignas(64) double tarea[TOPK_N];
  alignas(64) double tsc[TOPK_N];
  alignas(64) int    tcls[TOPK_N];
};

// device globals (NOT in poisoned workspace). Zero-init at load; graph-replay
// safe: d_c1/g_hist reset by k1's own tail, g_tbin overwritten before read.
__device__ u32 d_c1 = 0;
__device__ int g_tbin = 0;
__device__ int g_hist[NBINS];

__device__ __forceinline__ double dsigmoid(double x) { return 1.0 / (1.0 + exp(-x)); }

__device__ __forceinline__ int score_bin(double sc) {
  if (sc < 0.0) return 0;                          // masked
  return (int)(__float_as_uint((float)sc) >> 17);  // monotone for positive floats, < 8192
}

// sortable total order on fp32 bits (handles negatives, i.e. the -1.0 mask)
__device__ __forceinline__ u32 sortable32(float f) {
  u32 fb = __float_as_uint(f);
  return fb ^ ((fb & 0x80000000u) ? 0xFFFFFFFFu : 0x80000000u);
}

// Fence-cheap last-block detection (verified round 3):
//  - arrivers: drain own stores/atomics (vmcnt 0), one RELAXED agent RMW.
//  - last block only: one __threadfence() acquire before reading others' data.
__device__ __forceinline__ bool last_block(u32* ctr, u32 total) {
  __shared__ int isLast;
  asm volatile("s_waitcnt vmcnt(0)" ::: "memory");
  __syncthreads();
  if (threadIdx.x == 0) {
    u32 old = __hip_atomic_fetch_add(ctr, 1u, __ATOMIC_RELAXED, __HIP_MEMORY_SCOPE_AGENT);
    int last = (old == total - 1u) ? 1 : 0;
    if (last) {
      __hip_atomic_store(ctr, 0u, __ATOMIC_RELAXED, __HIP_MEMORY_SCOPE_AGENT);
      __threadfence();
    }
    isLast = last;
  }
  __syncthreads();
  return isLast != 0;
}

// ---------------- k1: decode + LDS hist + sparse merge; tiny t_bin tail ----
__global__ void __launch_bounds__(K1_B)
k1_decode(const float* __restrict__ ps, const float* __restrict__ pm,
          const float* __restrict__ pl, const float* __restrict__ anch,
          WS* __restrict__ ws) {
  __shared__ int histL[NBINS];   // 32 KB
  __shared__ int part[K1_B];
  const int tid  = threadIdx.x;
  const int gtid = blockIdx.x * K1_B + tid;

  for (int b = tid; b < NBINS; b += K1_B) histL[b] = 0;
  __syncthreads();

  {
    int a = gtid >> 2;
    int r = gtid & 3;
    if (a < N_ANCH) {
      const float* p; int W, base, lvl; double stride;
      if (a < NB0)      { p = ps; W = 80; base = 0;   lvl = 0; stride = 8.0; }
      else if (a < NB1) { p = pm; W = 40; base = NB0; lvl = 1; stride = 16.0; }
      else              { p = pl; W = 20; base = NB1; lvl = 2; stride = 32.0; }
      int e = a - base;
      int pos = e / 3;
      int k = e - 3 * pos;
      int HW = W * W;

      // class max/argmax + softmax denom, 20 classes per lane (teams of 4, wave-aligned)
      const float* pc = p + (size_t)(3 + k * 80) * HW + pos;
      double m = -1e300, ssum = 0.0; int am = 0;
      for (int t = 0; t < 20; ++t) {
        int c = r + 4 * t;
        double v = (double)pc[(size_t)c * HW];
        ssum += exp(v);
        if (v > m) { m = v; am = c; }
      }
      for (int off = 1; off <= 2; off <<= 1) {
        double om = __shfl_xor(m, off);
        int oam   = __shfl_xor(am, off);
        double os = __shfl_xor(ssum, off);
        ssum += os;
        if (om > m || (om == m && oam < am)) { m = om; am = oam; }
      }

      if (r == 0) {
        double sobj = dsigmoid((double)p[(size_t)k * HW + pos]);
        double sc = sobj * (exp(m) / ssum);

        int x = pos % W, y = pos / W;
        const float* pr = p + (size_t)(243 + k * 4) * HW + pos;
        double tx = (double)pr[0];
        double ty = (double)pr[(size_t)HW];
        double tw = (double)pr[(size_t)2 * HW];
        double th = (double)pr[(size_t)3 * HW];
        double cx = (dsigmoid(tx) + (double)x) * stride;
        double cy = (dsigmoid(ty) + (double)y) * stride;
        double aw = (double)anch[lvl * 6 + k * 2 + 0];
        double ah = (double)anch[lvl * 6 + k * 2 + 1];
        double bw = exp(tw) * aw;
        double bh = exp(th) * ah;
        double x1 = fmin(fmax((cx - 0.5 * bw) / IMGS, 0.0), 1.0);
        double y1 = fmin(fmax((cy - 0.5 * bh) / IMGS, 0.0), 1.0);
        double x2 = fmin(fmax((cx + 0.5 * bw) / IMGS, 0.0), 1.0);
        double y2 = fmin(fmax((cy + 0.5 * bh) / IMGS, 0.0), 1.0);

        ws->box[a][0] = x1; ws->box[a][1] = y1;
        ws->box[a][2] = x2; ws->box[a][3] = y2;
        ws->cls[a] = am;
        double scm = (sc >= CONF_T) ? sc : -1.0;
        ws->sc[a] = scm;
        u32 k32 = sortable32((float)scm);
        ws->skey[a] = ((u64)k32 << 32) | (u64)(0xFFFFFFFFu - (u32)a);
        atomicAdd(&histL[score_bin(scm)], 1);   // LDS: no device-atomic contention
      }
    }
  }
  __syncthreads();
  // sparse merge: <=128 nonzero bins per block
  for (int b = tid; b < NBINS; b += K1_B) {
    int v = histL[b];
    if (v) atomicAdd(&g_hist[b], v);
  }

  if (!last_block(&d_c1, K1_G)) return;

  // ---- tail (one block): t_bin from 8192-bin hist, then re-zero hist ----
  const int CH = NBINS / K1_B;   // 16 reversed bins per thread
  int h16[CH];
  int sum = 0;
#pragma unroll
  for (int rr = 0; rr < CH; ++rr) {
    h16[rr] = g_hist[NBINS - 1 - (tid * CH + rr)];
    sum += h16[rr];
  }
  part[tid] = sum;
  __syncthreads();
  for (int off = 1; off < K1_B; off <<= 1) {
    int v = (tid >= off) ? part[tid - off] : 0;
    __syncthreads();
    part[tid] += v;
    __syncthreads();
  }
  int cum = part[tid] - sum;
#pragma unroll
  for (int rr = 0; rr < CH; ++rr) {
    int b = NBINS - 1 - (tid * CH + rr);
    int prev = cum;
    cum += h16[rr];
    if (prev < TOPK_N && cum >= TOPK_N) g_tbin = b;   // unique crossing thread
  }
  // all g_hist loads happened before the scan barriers -> safe to zero now
  for (int i = tid; i < NBINS; i += K1_B) g_hist[i] = 0;
}

// ---------------- k2: direct rank + scatter (no compact kernel) ------------
// Block = 128 i x 8 j-slices. Per 1024-key chunk of skey: stage to regs,
// LDS-compact the keys >= thr (ballot + wave prefix), j-loop the survivors.
// rank(i) counted over subset-j equals global rank for every i that can
// scatter: key_i >= thr -> exact; key_i < thr -> every subset key (>=4096 of
// them, all in higher bins -> strictly larger) is counted -> r >= 4096.
__global__ void __launch_bounds__(K2_B)
k2_rank(WS* __restrict__ ws, float* __restrict__ out) {
  __shared__ u64 ckL[K2_B];          // 8 KB compacted chunk
  __shared__ int wcnt[16];
  __shared__ int part[K2_JS][128];
  const int tid  = threadIdx.x;
  const int il   = tid & 127;
  const int js   = tid >> 7;
  const int wid  = tid >> 6;
  const int lane = tid & 63;

  const int i = blockIdx.x * 128 + il;
  const bool act = (i < N_ANCH);
  u64 ki = act ? ws->skey[i] : 0ull;

  int tb = g_tbin;
  u32 thr = (tb > 0) ? (((u32)tb << 17) | 0x80000000u) : 0u;

  int cnt = 0;
  for (int c0 = 0; c0 < N_ANCH; c0 += K2_B) {
    int nc = min(K2_B, N_ANCH - c0);
    u64 k = 0; bool want = false;
    if (tid < nc) {
      k = ws->skey[c0 + tid];
      want = ((u32)(k >> 32)) >= thr;
    }
    u64 mk = __ballot(want);
    if (lane == 0) wcnt[wid] = (int)__popcll(mk);
    __syncthreads();
    int base = 0, nj = 0;
#pragma unroll
    for (int q = 0; q < 16; ++q) {
      int v = wcnt[q];
      if (q < wid) base += v;
      nj += v;
    }
    if (want) ckL[base + (int)__popcll(mk & ((1ull << lane) - 1ull))] = k;
    __syncthreads();
    for (int t = js; t < nj; t += K2_JS) cnt += (int)(ckL[t] > ki);
    __syncthreads();   // ckL/wcnt reused next chunk
  }
  part[js][il] = cnt;
  __syncthreads();

  if (js == 0 && act) {
    int r = 0;
#pragma unroll
    for (int q = 0; q < K2_JS; ++q) r += part[q][il];
    if (r < TOPK_N) {
      double b0 = ws->box[i][0], b1 = ws->box[i][1];
      double b2 = ws->box[i][2], b3 = ws->box[i][3];
      double s  = ws->sc[i];
      int    c  = ws->cls[i];
      ws->tbox[r][0] = b0; ws->tbox[r][1] = b1;
      ws->tbox[r][2] = b2; ws->tbox[r][3] = b3;
      ws->tarea[r] = (b2 - b0) * (b3 - b1);
      ws->tsc[r] = s;
      ws->tcls[r] = c;
      out[r * 4 + 0] = (float)b0;
      out[r * 4 + 1] = (float)b1;
      out[r * 4 + 2] = (float)b2;
      out[r * 4 + 3] = (float)b3;
      out[4 * TOPK_N + r] = (float)s;
      out[5 * TOPK_N + r] = (float)c;
    }
  }
}

// ---------------- k3: per-class NMS, suppression bit-matrix ----------------
// Greedy semantics identical: keep[i] = valid[i] && no kept j<i with IoU>T.
// Bit-matrix removes the per-candidate ballot dependency chain; the serial
// part is an n-iteration scalar u64 scan. Fallback (n > NMAXB): verified
// serial-ballot path from rounds 3-5 (never hit with ~51 avg per class).
__global__ void __launch_bounds__(64)
k3_nms(const WS* __restrict__ ws, float* __restrict__ out) {
  __shared__ int clsL[TOPK_N];            // 16 KB
  __shared__ int ridx[TOPK_N];            // 16 KB
  __shared__ double bxL[NMAXB][5];        // 10 KB
  __shared__ int vL[NMAXB];               // 1 KB
  __shared__ u64 supW[NMAXB][NMAXB / 64]; // 8 KB
  __shared__ int klist[TOPK_N];           // fallback only
  __shared__ unsigned char keepF[TOPK_N]; // fallback only

  const int lane = threadIdx.x;
  const int c = blockIdx.x;

  {
    const int4* src = (const int4*)ws->tcls;
    int4* dst = (int4*)clsL;
    for (int q = lane; q < TOPK_N / 4; q += 64) dst[q] = src[q];
  }
  __syncthreads();

  // stable compact: rows of class c in ascending rank order
  int n = 0;
  const u64 lt = (1ull << lane) - 1ull;
  for (int base = 0; base < TOPK_N; base += 64) {
    bool want = (clsL[base + lane] == c);
    u64 mk = __ballot(want);
    if (want) ridx[n + __popcll(mk & lt)] = base + lane;
    n += (int)__popcll(mk);
  }
  __syncthreads();
  if (n == 0) return;

  if (n <= NMAXB) {
    // stage this class's boxes + validity
    for (int q = lane; q < n; q += 64) {
      int r = ridx[q];
      bxL[q][0] = ws->tbox[r][0];
      bxL[q][1] = ws->tbox[r][1];
      bxL[q][2] = ws->tbox[r][2];
      bxL[q][3] = ws->tbox[r][3];
      bxL[q][4] = ws->tarea[r];
      vL[q] = (ws->tsc[r] >= CONF_T) ? 1 : 0;
    }
    __syncthreads();

    int nw = (n + 63) >> 6;
    for (int wq = 0; wq < nw; ++wq) {
      int j = wq * 64 + lane;
      int jc = (j < n) ? j : 0;
      double jx1 = bxL[jc][0], jy1 = bxL[jc][1];
      double jx2 = bxL[jc][2], jy2 = bxL[jc][3];
      double ja  = bxL[jc][4];
      for (int i = 0; i < n; ++i) {
        bool sup = false;
        if (j < i) {  // j<n implied
          double xx1 = fmax(bxL[i][0], jx1);
          double yy1 = fmax(bxL[i][1], jy1);
          double xx2 = fmin(bxL[i][2], jx2);
          double yy2 = fmin(bxL[i][3], jy2);
          double iw = fmax(1e-28, xx2 - xx1);
          double ih = fmax(1e-28, yy2 - yy1);
          double inter = iw * ih;
          double denom = bxL[i][4] + ja - inter + 1e-14;
          sup = inter > NMS_T * denom;
        }
        u64 bal = __ballot(sup);
        if (lane == 0) supW[i][wq] = bal;
      }
    }
    __syncthreads();

    // greedy scan, replicated uniformly across lanes (all LDS reads broadcast)
    u64 kw[NMAXB / 64] = {0, 0, 0, 0};
    for (int i = 0; i < n; ++i) {
      u64 s = 0;
      for (int w = 0; w < nw; ++w) s |= supW[i][w] & kw[w];
      if (vL[i] && s == 0ull) kw[i >> 6] |= 1ull << (i & 63);
    }
    for (int q = lane; q < n; q += 64)
      out[6 * TOPK_N + ridx[q]] = (float)((kw[q >> 6] >> (q & 63)) & 1ull);
    return;
  }

  // ---- fallback: serial-ballot greedy (verified rounds 3-5) ----
  {
    double kx1 = 0, ky1 = 0, kx2 = 0, ky2 = 0, ka = 0;
    int kn = 0;
    double nx1 = 0, ny1 = 0, nx2 = 0, ny2 = 0, na = 0, ns = -2.0;
    {
      int r = ridx[0];
      nx1 = ws->tbox[r][0]; ny1 = ws->tbox[r][1];
      nx2 = ws->tbox[r][2]; ny2 = ws->tbox[r][3];
      na = ws->tarea[r]; ns = ws->tsc[r];
    }
    for (int q = 0; q < n; ++q) {
      double cx1 = nx1, cy1 = ny1, cx2 = nx2, cy2 = ny2, ca = na, cs = ns;
      int rcur = ridx[q];
      if (q + 1 < n) {
        int r2 = ridx[q + 1];
        nx1 = ws->tbox[r2][0]; ny1 = ws->tbox[r2][1];
        nx2 = ws->tbox[r2][2]; ny2 = ws->tbox[r2][3];
        na = ws->tarea[r2]; ns = ws->tsc[r2];
      }
      bool sup = false;
      if (lane < kn && lane < 64) {
        double xx1 = fmax(cx1, kx1), yy1 = fmax(cy1, ky1);
        double xx2 = fmin(cx2, kx2), yy2 = fmin(cy2, ky2);
        double iw = fmax(1e-28, xx2 - xx1);
        double ih = fmax(1e-28, yy2 - yy1);
        double inter = iw * ih;
        double denom = ca + ka - inter + 1e-14;
        sup = inter > NMS_T * denom;
      }
      for (int kb = 64; kb < kn; kb += 64) {
        if (kb + lane < kn) {
          int kr = klist[kb + lane];
          double ox1 = ws->tbox[kr][0], oy1 = ws->tbox[kr][1];
          double ox2 = ws->tbox[kr][2], oy2 = ws->tbox[kr][3];
          double oa = ws->tarea[kr];
          double xx1 = fmax(cx1, ox1), yy1 = fmax(cy1, oy1);
          double xx2 = fmin(cx2, ox2), yy2 = fmin(cy2, oy2);
          double iw = fmax(1e-28, xx2 - xx1);
          double ih = fmax(1e-28, yy2 - yy1);
          double inter = iw * ih;
          double denom = ca + oa - inter + 1e-14;
          sup = sup || (inter > NMS_T * denom);
        }
      }
      u64 anyb = __ballot(sup);
      bool valid = (cs >= CONF_T);
      bool kp = valid && (anyb == 0ull);
      if (kp) {
        if (kn < 64 && lane == kn) { kx1 = cx1; ky1 = cy1; kx2 = cx2; ky2 = cy2; ka = ca; }
        if (lane == 0) klist[kn] = rcur;
        ++kn;
      }
      if (lane == 0) keepF[q] = kp ? 1 : 0;
    }
    __syncthreads();
    for (int q = lane; q < n; q += 64)
      out[6 * TOPK_N + ridx[q]] = (float)keepF[q];
  }
}

extern "C" void kernel_launch(void* const* d_in, const int* in_sizes, int n_in,
                              void* d_out, int out_size, void* d_ws, size_t ws_size,
                              hipStream_t stream) {
  const float* ps   = (const float*)d_in[0];
  const float* pm   = (const float*)d_in[1];
  const float* pl   = (const float*)d_in[2];
  const float* anch = (const float*)d_in[3];
  float* out = (float*)d_out;
  WS* ws = (WS*)d_ws;

  k1_decode<<<dim3(K1_G), dim3(K1_B), 0, stream>>>(ps, pm, pl, anch, ws);
  k2_rank  <<<dim3(K2_G), dim3(K2_B), 0, stream>>>(ws, out);
  k3_nms   <<<dim3(NCLS), dim3(64), 0, stream>>>(ws, out);
}

// Round 7
// 155.122 us; speedup vs baseline: 1.1190x; 1.1190x over previous
//
#include <hip/hip_runtime.h>
#include <cstdint>
#include <cstddef>

#define N_ANCH 25200
#define NB0 19200
#define NB1 24000
#define TOPK_N 4096
#define CONF_T 0.001
#define NMS_T 0.6
#define IMGS 640.0
#define NBINS 8192       // fp32 bits >> 17 (exponent + 6 mantissa bits)

#define K1_B 512
#define K1_G 197         // ceil(25200*4 / 512)
#define K2_B 1024
#define K2_G 25          // ceil(25200 / 1024)
#define K3_B 1024
#define K3_IC 128        // i-chunk per block
#define K3_JS 8          // j-slices per block
#define K3_G 197         // ceil(25200 / 128) — covers any m (early-exit above m)
#define CAPK 6144        // LDS key cap (48 KB); m>CAPK falls back to global
#define NCLS 80
#define NMAXB 256        // bit-matrix NMS path cap (fallback above)

typedef unsigned long long u64;
typedef unsigned int u32;

struct WS {
  alignas(64) double sc[N_ANCH];       // masked score (sc or -1.0), fp64
  alignas(64) double box[N_ANCH][4];   // clipped normalized boxes, fp64
  alignas(64) int    cls[N_ANCH];
  alignas(64) u64    skey[N_ANCH];     // (sortable fp32 bits << 32) | (~anchor id)
  alignas(64) u64    ckey[N_ANCH];     // compacted subset keys (arbitrary order)
  alignas(64) double tbox[TOPK_N][4];
  alignas(64) double tarea[TOPK_N];
  alignas(64) double tsc[TOPK_N];
  alignas(64) int    tcls[TOPK_N];
};

// device globals (NOT in poisoned workspace). Zero-init at load; graph-replay
// safe: d_c1/g_hist reset by k1's own tail, g_tbin overwritten before read,
// g_m reset by k4 (runs after its only reader k3).
__device__ u32 d_c1 = 0;
__device__ u32 g_m  = 0;
__device__ int g_tbin = 0;
__device__ int g_hist[NBINS];

__device__ __forceinline__ double dsigmoid(double x) { return 1.0 / (1.0 + exp(-x)); }

__device__ __forceinline__ int score_bin(double sc) {
  if (sc < 0.0) return 0;                          // masked
  return (int)(__float_as_uint((float)sc) >> 17);  // monotone for positive floats, < 8192
}

// sortable total order on fp32 bits (handles negatives, i.e. the -1.0 mask)
__device__ __forceinline__ u32 sortable32(float f) {
  u32 fb = __float_as_uint(f);
  return fb ^ ((fb & 0x80000000u) ? 0xFFFFFFFFu : 0x80000000u);
}

// Fence-cheap last-block detection (verified round 3):
//  - arrivers: drain own stores/atomics (vmcnt 0), one RELAXED agent RMW.
//  - last block only: one __threadfence() acquire before reading others' data.
__device__ __forceinline__ bool last_block(u32* ctr, u32 total) {
  __shared__ int isLast;
  asm volatile("s_waitcnt vmcnt(0)" ::: "memory");
  __syncthreads();
  if (threadIdx.x == 0) {
    u32 old = __hip_atomic_fetch_add(ctr, 1u, __ATOMIC_RELAXED, __HIP_MEMORY_SCOPE_AGENT);
    int last = (old == total - 1u) ? 1 : 0;
    if (last) {
      __hip_atomic_store(ctr, 0u, __ATOMIC_RELAXED, __HIP_MEMORY_SCOPE_AGENT);
      __threadfence();
    }
    isLast = last;
  }
  __syncthreads();
  return isLast != 0;
}

// ---------------- k1: decode + LDS hist + sparse merge; tiny t_bin tail ----
// (verified round 6 — unchanged)
__global__ void __launch_bounds__(K1_B)
k1_decode(const float* __restrict__ ps, const float* __restrict__ pm,
          const float* __restrict__ pl, const float* __restrict__ anch,
          WS* __restrict__ ws) {
  __shared__ int histL[NBINS];   // 32 KB
  __shared__ int part[K1_B];
  const int tid  = threadIdx.x;
  const int gtid = blockIdx.x * K1_B + tid;

  for (int b = tid; b < NBINS; b += K1_B) histL[b] = 0;
  __syncthreads();

  {
    int a = gtid >> 2;
    int r = gtid & 3;
    if (a < N_ANCH) {
      const float* p; int W, base, lvl; double stride;
      if (a < NB0)      { p = ps; W = 80; base = 0;   lvl = 0; stride = 8.0; }
      else if (a < NB1) { p = pm; W = 40; base = NB0; lvl = 1; stride = 16.0; }
      else              { p = pl; W = 20; base = NB1; lvl = 2; stride = 32.0; }
      int e = a - base;
      int pos = e / 3;
      int k = e - 3 * pos;
      int HW = W * W;

      // class max/argmax + softmax denom, 20 classes per lane (teams of 4, wave-aligned)
      const float* pc = p + (size_t)(3 + k * 80) * HW + pos;
      double m = -1e300, ssum = 0.0; int am = 0;
      for (int t = 0; t < 20; ++t) {
        int c = r + 4 * t;
        double v = (double)pc[(size_t)c * HW];
        ssum += exp(v);
        if (v > m) { m = v; am = c; }
      }
      for (int off = 1; off <= 2; off <<= 1) {
        double om = __shfl_xor(m, off);
        int oam   = __shfl_xor(am, off);
        double os = __shfl_xor(ssum, off);
        ssum += os;
        if (om > m || (om == m && oam < am)) { m = om; am = oam; }
      }

      if (r == 0) {
        double sobj = dsigmoid((double)p[(size_t)k * HW + pos]);
        double sc = sobj * (exp(m) / ssum);

        int x = pos % W, y = pos / W;
        const float* pr = p + (size_t)(243 + k * 4) * HW + pos;
        double tx = (double)pr[0];
        double ty = (double)pr[(size_t)HW];
        double tw = (double)pr[(size_t)2 * HW];
        double th = (double)pr[(size_t)3 * HW];
        double cx = (dsigmoid(tx) + (double)x) * stride;
        double cy = (dsigmoid(ty) + (double)y) * stride;
        double aw = (double)anch[lvl * 6 + k * 2 + 0];
        double ah = (double)anch[lvl * 6 + k * 2 + 1];
        double bw = exp(tw) * aw;
        double bh = exp(th) * ah;
        double x1 = fmin(fmax((cx - 0.5 * bw) / IMGS, 0.0), 1.0);
        double y1 = fmin(fmax((cy - 0.5 * bh) / IMGS, 0.0), 1.0);
        double x2 = fmin(fmax((cx + 0.5 * bw) / IMGS, 0.0), 1.0);
        double y2 = fmin(fmax((cy + 0.5 * bh) / IMGS, 0.0), 1.0);

        ws->box[a][0] = x1; ws->box[a][1] = y1;
        ws->box[a][2] = x2; ws->box[a][3] = y2;
        ws->cls[a] = am;
        double scm = (sc >= CONF_T) ? sc : -1.0;
        ws->sc[a] = scm;
        u32 k32 = sortable32((float)scm);
        ws->skey[a] = ((u64)k32 << 32) | (u64)(0xFFFFFFFFu - (u32)a);
        atomicAdd(&histL[score_bin(scm)], 1);   // LDS: no device-atomic contention
      }
    }
  }
  __syncthreads();
  // sparse merge: <=128 nonzero bins per block
  for (int b = tid; b < NBINS; b += K1_B) {
    int v = histL[b];
    if (v) atomicAdd(&g_hist[b], v);
  }

  if (!last_block(&d_c1, K1_G)) return;

  // ---- tail (one block): t_bin from 8192-bin hist, then re-zero hist ----
  const int CH = NBINS / K1_B;   // 16 reversed bins per thread
  int h16[CH];
  int sum = 0;
#pragma unroll
  for (int rr = 0; rr < CH; ++rr) {
    h16[rr] = g_hist[NBINS - 1 - (tid * CH + rr)];
    sum += h16[rr];
  }
  part[tid] = sum;
  __syncthreads();
  for (int off = 1; off < K1_B; off <<= 1) {
    int v = (tid >= off) ? part[tid - off] : 0;
    __syncthreads();
    part[tid] += v;
    __syncthreads();
  }
  int cum = part[tid] - sum;
#pragma unroll
  for (int rr = 0; rr < CH; ++rr) {
    int b = NBINS - 1 - (tid * CH + rr);
    int prev = cum;
    cum += h16[rr];
    if (prev < TOPK_N && cum >= TOPK_N) g_tbin = b;   // unique crossing thread
  }
  // all g_hist loads happened before the scan barriers -> safe to zero now
  for (int i = tid; i < NBINS; i += K1_B) g_hist[i] = 0;
}

// ---------------- k2: parallel compact (order-free key append) -------------
// (verified round 5 — unchanged)
__global__ void __launch_bounds__(K2_B)
k2_compact(WS* __restrict__ ws) {
  int i = blockIdx.x * K2_B + threadIdx.x;
  int tb = g_tbin;
  u32 thr = (tb > 0) ? (((u32)tb << 17) | 0x80000000u) : 0u;
  bool want = false; u64 key = 0;
  if (i < N_ANCH) {
    key = ws->skey[i];
    want = ((u32)(key >> 32)) >= thr;   // == (binv >= t_bin), masked excluded for tb>0
  }
  u64 mask = __ballot(want);
  if (mask) {
    int lane = threadIdx.x & 63;
    int lead = __ffsll((long long)mask) - 1;
    int pre  = __popcll(mask & ((1ull << lane) - 1ull));
    u32 base = 0;
    if (lane == lead) base = atomicAdd(&g_m, (u32)__popcll(mask));
    base = __shfl(base, lead);
    if (want) ws->ckey[base + pre] = key;
  }
}

// ---------------- k3: rank within subset + direct scatter ------------------
// (verified round 5 — unchanged) rank[i] = #{ j in subset : key_j > key_i };
// strict total order (ties break by lower anchor id via ~a) = stable top_k.
__global__ void __launch_bounds__(K3_B)
k3_rank(WS* __restrict__ ws, float* __restrict__ out) {
  int m = (int)g_m;
  int base = blockIdx.x * K3_IC;
  if (base >= m) return;                 // block-uniform exit

  __shared__ u64 skL[CAPK];              // 48 KB
  __shared__ int part[K3_JS][K3_IC];     // 4 KB
  const int tid = threadIdx.x;
  const int il = tid & (K3_IC - 1);
  const int js = tid >> 7;

  int mc = (m < CAPK) ? m : CAPK;
  for (int t = tid; t < mc; t += K3_B) skL[t] = ws->ckey[t];
  __syncthreads();

  int pos = base + il;
  bool active = (pos < m);
  u64 ki = 0;
  if (active) ki = (pos < CAPK) ? skL[pos] : ws->ckey[pos];

  int jlen = (m + K3_JS - 1) / K3_JS;
  int j0 = js * jlen;
  int jend = min(j0 + jlen, m);
  int cnt = 0;
  int jmid = min(jend, CAPK);
  for (int t = j0; t < jmid; ++t) cnt += (int)(skL[t] > ki);
  for (int t = max(j0, CAPK); t < jend; ++t) cnt += (int)(ws->ckey[t] > ki);
  part[js][il] = cnt;
  __syncthreads();

  if (js == 0 && active) {
    int r = 0;
#pragma unroll
    for (int q = 0; q < K3_JS; ++q) r += part[q][il];
    if (r < TOPK_N) {
      u32 aid = 0xFFFFFFFFu - (u32)(ki & 0xFFFFFFFFu);
      double b0 = ws->box[aid][0], b1 = ws->box[aid][1];
      double b2 = ws->box[aid][2], b3 = ws->box[aid][3];
      double s  = ws->sc[aid];
      int    c  = ws->cls[aid];
      ws->tbox[r][0] = b0; ws->tbox[r][1] = b1;
      ws->tbox[r][2] = b2; ws->tbox[r][3] = b3;
      ws->tarea[r] = (b2 - b0) * (b3 - b1);
      ws->tsc[r] = s;
      ws->tcls[r] = c;
      out[r * 4 + 0] = (float)b0;
      out[r * 4 + 1] = (float)b1;
      out[r * 4 + 2] = (float)b2;
      out[r * 4 + 3] = (float)b3;
      out[4 * TOPK_N + r] = (float)s;
      out[5 * TOPK_N + r] = (float)c;
    }
  }
}

// ---------------- k4: per-class NMS, suppression bit-matrix ----------------
// (verified round 6 — unchanged, + g_m reset for graph replay)
__global__ void __launch_bounds__(64)
k4_nms(const WS* __restrict__ ws, float* __restrict__ out) {
  __shared__ int clsL[TOPK_N];            // 16 KB
  __shared__ int ridx[TOPK_N];            // 16 KB
  __shared__ double bxL[NMAXB][5];        // 10 KB
  __shared__ int vL[NMAXB];               // 1 KB
  __shared__ u64 supW[NMAXB][NMAXB / 64]; // 8 KB
  __shared__ int klist[TOPK_N];           // fallback only
  __shared__ unsigned char keepF[TOPK_N]; // fallback only

  const int lane = threadIdx.x;
  const int c = blockIdx.x;

  if (c == 0 && lane == 0) g_m = 0;      // reset for next replay (k3 already done)

  {
    const int4* src = (const int4*)ws->tcls;
    int4* dst = (int4*)clsL;
    for (int q = lane; q < TOPK_N / 4; q += 64) dst[q] = src[q];
  }
  __syncthreads();

  // stable compact: rows of class c in ascending rank order
  int n = 0;
  const u64 lt = (1ull << lane) - 1ull;
  for (int base = 0; base < TOPK_N; base += 64) {
    bool want = (clsL[base + lane] == c);
    u64 mk = __ballot(want);
    if (want) ridx[n + __popcll(mk & lt)] = base + lane;
    n += (int)__popcll(mk);
  }
  __syncthreads();
  if (n == 0) return;

  if (n <= NMAXB) {
    // stage this class's boxes + validity
    for (int q = lane; q < n; q += 64) {
      int r = ridx[q];
      bxL[q][0] = ws->tbox[r][0];
      bxL[q][1] = ws->tbox[r][1];
      bxL[q][2] = ws->tbox[r][2];
      bxL[q][3] = ws->tbox[r][3];
      bxL[q][4] = ws->tarea[r];
      vL[q] = (ws->tsc[r] >= CONF_T) ? 1 : 0;
    }
    __syncthreads();

    int nw = (n + 63) >> 6;
    for (int wq = 0; wq < nw; ++wq) {
      int j = wq * 64 + lane;
      int jc = (j < n) ? j : 0;
      double jx1 = bxL[jc][0], jy1 = bxL[jc][1];
      double jx2 = bxL[jc][2], jy2 = bxL[jc][3];
      double ja  = bxL[jc][4];
      for (int i = 0; i < n; ++i) {
        bool sup = false;
        if (j < i) {  // j<n implied
          double xx1 = fmax(bxL[i][0], jx1);
          double yy1 = fmax(bxL[i][1], jy1);
          double xx2 = fmin(bxL[i][2], jx2);
          double yy2 = fmin(bxL[i][3], jy2);
          double iw = fmax(1e-28, xx2 - xx1);
          double ih = fmax(1e-28, yy2 - yy1);
          double inter = iw * ih;
          double denom = bxL[i][4] + ja - inter + 1e-14;
          sup = inter > NMS_T * denom;
        }
        u64 bal = __ballot(sup);
        if (lane == 0) supW[i][wq] = bal;
      }
    }
    __syncthreads();

    // greedy scan, replicated uniformly across lanes (all LDS reads broadcast)
    u64 kw[NMAXB / 64] = {0, 0, 0, 0};
    for (int i = 0; i < n; ++i) {
      u64 s = 0;
      for (int w = 0; w < nw; ++w) s |= supW[i][w] & kw[w];
      if (vL[i] && s == 0ull) kw[i >> 6] |= 1ull << (i & 63);
    }
    for (int q = lane; q < n; q += 64)
      out[6 * TOPK_N + ridx[q]] = (float)((kw[q >> 6] >> (q & 63)) & 1ull);
    return;
  }

  // ---- fallback: serial-ballot greedy (verified rounds 3-5) ----
  {
    double kx1 = 0, ky1 = 0, kx2 = 0, ky2 = 0, ka = 0;
    int kn = 0;
    double nx1 = 0, ny1 = 0, nx2 = 0, ny2 = 0, na = 0, ns = -2.0;
    {
      int r = ridx[0];
      nx1 = ws->tbox[r][0]; ny1 = ws->tbox[r][1];
      nx2 = ws->tbox[r][2]; ny2 = ws->tbox[r][3];
      na = ws->tarea[r]; ns = ws->tsc[r];
    }
    for (int q = 0; q < n; ++q) {
      double cx1 = nx1, cy1 = ny1, cx2 = nx2, cy2 = ny2, ca = na, cs = ns;
      int rcur = ridx[q];
      if (q + 1 < n) {
        int r2 = ridx[q + 1];
        nx1 = ws->tbox[r2][0]; ny1 = ws->tbox[r2][1];
        nx2 = ws->tbox[r2][2]; ny2 = ws->tbox[r2][3];
        na = ws->tarea[r2]; ns = ws->tsc[r2];
      }
      bool sup = false;
      if (lane < kn && lane < 64) {
        double xx1 = fmax(cx1, kx1), yy1 = fmax(cy1, ky1);
        double xx2 = fmin(cx2, kx2), yy2 = fmin(cy2, ky2);
        double iw = fmax(1e-28, xx2 - xx1);
        double ih = fmax(1e-28, yy2 - yy1);
        double inter = iw * ih;
        double denom = ca + ka - inter + 1e-14;
        sup = inter > NMS_T * denom;
      }
      for (int kb = 64; kb < kn; kb += 64) {
        if (kb + lane < kn) {
          int kr = klist[kb + lane];
          double ox1 = ws->tbox[kr][0], oy1 = ws->tbox[kr][1];
          double ox2 = ws->tbox[kr][2], oy2 = ws->tbox[kr][3];
          double oa = ws->tarea[kr];
          double xx1 = fmax(cx1, ox1), yy1 = fmax(cy1, oy1);
          double xx2 = fmin(cx2, ox2), yy2 = fmin(cy2, oy2);
          double iw = fmax(1e-28, xx2 - xx1);
          double ih = fmax(1e-28, yy2 - yy1);
          double inter = iw * ih;
          double denom = ca + oa - inter + 1e-14;
          sup = sup || (inter > NMS_T * denom);
        }
      }
      u64 anyb = __ballot(sup);
      bool valid = (cs >= CONF_T);
      bool kp = valid && (anyb == 0ull);
      if (kp) {
        if (kn < 64 && lane == kn) { kx1 = cx1; ky1 = cy1; kx2 = cx2; ky2 = cy2; ka = ca; }
        if (lane == 0) klist[kn] = rcur;
        ++kn;
      }
      if (lane == 0) keepF[q] = kp ? 1 : 0;
    }
    __syncthreads();
    for (int q = lane; q < n; q += 64)
      out[6 * TOPK_N + ridx[q]] = (float)keepF[q];
  }
}

extern "C" void kernel_launch(void* const* d_in, const int* in_sizes, int n_in,
                              void* d_out, int out_size, void* d_ws, size_t ws_size,
                              hipStream_t stream) {
  const float* ps   = (const float*)d_in[0];
  const float* pm   = (const float*)d_in[1];
  const float* pl   = (const float*)d_in[2];
  const float* anch = (const float*)d_in[3];
  float* out = (float*)d_out;
  WS* ws = (WS*)d_ws;

  k1_decode <<<dim3(K1_G), dim3(K1_B), 0, stream>>>(ps, pm, pl, anch, ws);
  k2_compact<<<dim3(K2_G), dim3(K2_B), 0, stream>>>(ws);
  k3_rank   <<<dim3(K3_G), dim3(K3_B), 0, stream>>>(ws, out);
  k4_nms    <<<dim3(NCLS), dim3(64), 0, stream>>>(ws, out);
}

// Round 8
// 148.920 us; speedup vs baseline: 1.1656x; 1.0416x over previous
//
#include <hip/hip_runtime.h>
#include <cstdint>
#include <cstddef>

#define N_ANCH 25200
#define NB0 19200
#define NB1 24000
#define TOPK_N 4096
#define CONF_T 0.001
#define NMS_T 0.6
#define IMGS 640.0
#define NBINS 8192       // fp32 bits >> 17 (exponent + 6 mantissa bits)

#define K1_B 512
#define K1_G 197         // ceil(25200*4 / 512)
#define K2_B 1024
#define K2_G 25          // ceil(25200 / 1024)
#define K3_B 1024
#define K3_IC 128        // i-chunk per block
#define K3_JS 8          // j-slices per block
#define K3_G 197         // ceil(25200 / 128) — covers any m (early-exit above m)
#define CAPK 6144        // LDS key cap (48 KB); m>CAPK falls back to global
#define NCLS 80
#define NMAXB 256        // bit-matrix NMS path cap (fallback above)

typedef unsigned long long u64;
typedef unsigned int u32;

struct WS {
  alignas(64) double sc[N_ANCH];       // masked score (sc or -1.0), fp64
  alignas(64) double box[N_ANCH][4];   // clipped normalized boxes, fp64
  alignas(64) int    cls[N_ANCH];
  alignas(64) u64    skey[N_ANCH];     // (sortable fp32 bits << 32) | (~anchor id)
  alignas(64) u64    ckey[N_ANCH];     // compacted subset keys (arbitrary order)
  alignas(64) double tbox[TOPK_N][4];
  alignas(64) double tarea[TOPK_N];
  alignas(64) double tsc[TOPK_N];
  alignas(64) int    tcls[TOPK_N];
};

// device globals (NOT in poisoned workspace). Zero-init at load; graph-replay
// safe: d_c1/g_hist reset by k1's own tail, g_tbin overwritten before read,
// g_m reset by k4 (runs after its only reader k3).
__device__ u32 d_c1 = 0;
__device__ u32 g_m  = 0;
__device__ int g_tbin = 0;
__device__ int g_hist[NBINS];

__device__ __forceinline__ double dsigmoid(double x) { return 1.0 / (1.0 + exp(-x)); }

__device__ __forceinline__ int score_bin(double sc) {
  if (sc < 0.0) return 0;                          // masked
  return (int)(__float_as_uint((float)sc) >> 17);  // monotone for positive floats, < 8192
}

// sortable total order on fp32 bits (handles negatives, i.e. the -1.0 mask)
__device__ __forceinline__ u32 sortable32(float f) {
  u32 fb = __float_as_uint(f);
  return fb ^ ((fb & 0x80000000u) ? 0xFFFFFFFFu : 0x80000000u);
}

// Fence-cheap last-block detection (verified round 3):
//  - arrivers: drain own stores/atomics (vmcnt 0), one RELAXED agent RMW.
//  - last block only: one __threadfence() acquire before reading others' data.
__device__ __forceinline__ bool last_block(u32* ctr, u32 total) {
  __shared__ int isLast;
  asm volatile("s_waitcnt vmcnt(0)" ::: "memory");
  __syncthreads();
  if (threadIdx.x == 0) {
    u32 old = __hip_atomic_fetch_add(ctr, 1u, __ATOMIC_RELAXED, __HIP_MEMORY_SCOPE_AGENT);
    int last = (old == total - 1u) ? 1 : 0;
    if (last) {
      __hip_atomic_store(ctr, 0u, __ATOMIC_RELAXED, __HIP_MEMORY_SCOPE_AGENT);
      __threadfence();
    }
    isLast = last;
  }
  __syncthreads();
  return isLast != 0;
}

// ---------------- k1: decode + LDS hist + sparse merge; tiny t_bin tail ----
// (verified round 6 — unchanged)
__global__ void __launch_bounds__(K1_B)
k1_decode(const float* __restrict__ ps, const float* __restrict__ pm,
          const float* __restrict__ pl, const float* __restrict__ anch,
          WS* __restrict__ ws) {
  __shared__ int histL[NBINS];   // 32 KB
  __shared__ int part[K1_B];
  const int tid  = threadIdx.x;
  const int gtid = blockIdx.x * K1_B + tid;

  for (int b = tid; b < NBINS; b += K1_B) histL[b] = 0;
  __syncthreads();

  {
    int a = gtid >> 2;
    int r = gtid & 3;
    if (a < N_ANCH) {
      const float* p; int W, base, lvl; double stride;
      if (a < NB0)      { p = ps; W = 80; base = 0;   lvl = 0; stride = 8.0; }
      else if (a < NB1) { p = pm; W = 40; base = NB0; lvl = 1; stride = 16.0; }
      else              { p = pl; W = 20; base = NB1; lvl = 2; stride = 32.0; }
      int e = a - base;
      int pos = e / 3;
      int k = e - 3 * pos;
      int HW = W * W;

      // class max/argmax + softmax denom, 20 classes per lane (teams of 4, wave-aligned)
      const float* pc = p + (size_t)(3 + k * 80) * HW + pos;
      double m = -1e300, ssum = 0.0; int am = 0;
      for (int t = 0; t < 20; ++t) {
        int c = r + 4 * t;
        double v = (double)pc[(size_t)c * HW];
        ssum += exp(v);
        if (v > m) { m = v; am = c; }
      }
      for (int off = 1; off <= 2; off <<= 1) {
        double om = __shfl_xor(m, off);
        int oam   = __shfl_xor(am, off);
        double os = __shfl_xor(ssum, off);
        ssum += os;
        if (om > m || (om == m && oam < am)) { m = om; am = oam; }
      }

      if (r == 0) {
        double sobj = dsigmoid((double)p[(size_t)k * HW + pos]);
        double sc = sobj * (exp(m) / ssum);

        int x = pos % W, y = pos / W;
        const float* pr = p + (size_t)(243 + k * 4) * HW + pos;
        double tx = (double)pr[0];
        double ty = (double)pr[(size_t)HW];
        double tw = (double)pr[(size_t)2 * HW];
        double th = (double)pr[(size_t)3 * HW];
        double cx = (dsigmoid(tx) + (double)x) * stride;
        double cy = (dsigmoid(ty) + (double)y) * stride;
        double aw = (double)anch[lvl * 6 + k * 2 + 0];
        double ah = (double)anch[lvl * 6 + k * 2 + 1];
        double bw = exp(tw) * aw;
        double bh = exp(th) * ah;
        double x1 = fmin(fmax((cx - 0.5 * bw) / IMGS, 0.0), 1.0);
        double y1 = fmin(fmax((cy - 0.5 * bh) / IMGS, 0.0), 1.0);
        double x2 = fmin(fmax((cx + 0.5 * bw) / IMGS, 0.0), 1.0);
        double y2 = fmin(fmax((cy + 0.5 * bh) / IMGS, 0.0), 1.0);

        ws->box[a][0] = x1; ws->box[a][1] = y1;
        ws->box[a][2] = x2; ws->box[a][3] = y2;
        ws->cls[a] = am;
        double scm = (sc >= CONF_T) ? sc : -1.0;
        ws->sc[a] = scm;
        u32 k32 = sortable32((float)scm);
        ws->skey[a] = ((u64)k32 << 32) | (u64)(0xFFFFFFFFu - (u32)a);
        atomicAdd(&histL[score_bin(scm)], 1);   // LDS: no device-atomic contention
      }
    }
  }
  __syncthreads();
  // sparse merge: <=128 nonzero bins per block
  for (int b = tid; b < NBINS; b += K1_B) {
    int v = histL[b];
    if (v) atomicAdd(&g_hist[b], v);
  }

  if (!last_block(&d_c1, K1_G)) return;

  // ---- tail (one block): t_bin from 8192-bin hist, then re-zero hist ----
  const int CH = NBINS / K1_B;   // 16 reversed bins per thread
  int h16[CH];
  int sum = 0;
#pragma unroll
  for (int rr = 0; rr < CH; ++rr) {
    h16[rr] = g_hist[NBINS - 1 - (tid * CH + rr)];
    sum += h16[rr];
  }
  part[tid] = sum;
  __syncthreads();
  for (int off = 1; off < K1_B; off <<= 1) {
    int v = (tid >= off) ? part[tid - off] : 0;
    __syncthreads();
    part[tid] += v;
    __syncthreads();
  }
  int cum = part[tid] - sum;
#pragma unroll
  for (int rr = 0; rr < CH; ++rr) {
    int b = NBINS - 1 - (tid * CH + rr);
    int prev = cum;
    cum += h16[rr];
    if (prev < TOPK_N && cum >= TOPK_N) g_tbin = b;   // unique crossing thread
  }
  // all g_hist loads happened before the scan barriers -> safe to zero now
  for (int i = tid; i < NBINS; i += K1_B) g_hist[i] = 0;
}

// ---------------- k2: parallel compact (order-free key append) -------------
// (verified round 5 — unchanged)
__global__ void __launch_bounds__(K2_B)
k2_compact(WS* __restrict__ ws) {
  int i = blockIdx.x * K2_B + threadIdx.x;
  int tb = g_tbin;
  u32 thr = (tb > 0) ? (((u32)tb << 17) | 0x80000000u) : 0u;
  bool want = false; u64 key = 0;
  if (i < N_ANCH) {
    key = ws->skey[i];
    want = ((u32)(key >> 32)) >= thr;   // == (binv >= t_bin), masked excluded for tb>0
  }
  u64 mask = __ballot(want);
  if (mask) {
    int lane = threadIdx.x & 63;
    int lead = __ffsll((long long)mask) - 1;
    int pre  = __popcll(mask & ((1ull << lane) - 1ull));
    u32 base = 0;
    if (lane == lead) base = atomicAdd(&g_m, (u32)__popcll(mask));
    base = __shfl(base, lead);
    if (want) ws->ckey[base + pre] = key;
  }
}

// ---------------- k3: rank within subset + direct scatter ------------------
// (verified round 5 — unchanged) rank[i] = #{ j in subset : key_j > key_i };
// strict total order (ties break by lower anchor id via ~a) = stable top_k.
__global__ void __launch_bounds__(K3_B)
k3_rank(WS* __restrict__ ws, float* __restrict__ out) {
  int m = (int)g_m;
  int base = blockIdx.x * K3_IC;
  if (base >= m) return;                 // block-uniform exit

  __shared__ u64 skL[CAPK];              // 48 KB
  __shared__ int part[K3_JS][K3_IC];     // 4 KB
  const int tid = threadIdx.x;
  const int il = tid & (K3_IC - 1);
  const int js = tid >> 7;

  int mc = (m < CAPK) ? m : CAPK;
  for (int t = tid; t < mc; t += K3_B) skL[t] = ws->ckey[t];
  __syncthreads();

  int pos = base + il;
  bool active = (pos < m);
  u64 ki = 0;
  if (active) ki = (pos < CAPK) ? skL[pos] : ws->ckey[pos];

  int jlen = (m + K3_JS - 1) / K3_JS;
  int j0 = js * jlen;
  int jend = min(j0 + jlen, m);
  int cnt = 0;
  int jmid = min(jend, CAPK);
  for (int t = j0; t < jmid; ++t) cnt += (int)(skL[t] > ki);
  for (int t = max(j0, CAPK); t < jend; ++t) cnt += (int)(ws->ckey[t] > ki);
  part[js][il] = cnt;
  __syncthreads();

  if (js == 0 && active) {
    int r = 0;
#pragma unroll
    for (int q = 0; q < K3_JS; ++q) r += part[q][il];
    if (r < TOPK_N) {
      u32 aid = 0xFFFFFFFFu - (u32)(ki & 0xFFFFFFFFu);
      double b0 = ws->box[aid][0], b1 = ws->box[aid][1];
      double b2 = ws->box[aid][2], b3 = ws->box[aid][3];
      double s  = ws->sc[aid];
      int    c  = ws->cls[aid];
      ws->tbox[r][0] = b0; ws->tbox[r][1] = b1;
      ws->tbox[r][2] = b2; ws->tbox[r][3] = b3;
      ws->tarea[r] = (b2 - b0) * (b3 - b1);
      ws->tsc[r] = s;
      ws->tcls[r] = c;
      out[r * 4 + 0] = (float)b0;
      out[r * 4 + 1] = (float)b1;
      out[r * 4 + 2] = (float)b2;
      out[r * 4 + 3] = (float)b3;
      out[4 * TOPK_N + r] = (float)s;
      out[5 * TOPK_N + r] = (float)c;
    }
  }
}

// ---------------- k4: per-class NMS, suppression bit-matrix ----------------
// Round-8 fix: greedy-scan keep mask kw[] was runtime-indexed -> scratch
// (Rule #20; 46 us, VALUBusy 0.5%). Now 4 named registers with static
// selection; supW rows zero-padded to 4 words so the OR uses fixed indices.
__global__ void __launch_bounds__(64)
k4_nms(const WS* __restrict__ ws, float* __restrict__ out) {
  __shared__ int clsL[TOPK_N];            // 16 KB
  __shared__ int ridx[TOPK_N];            // 16 KB
  __shared__ double bxL[NMAXB][5];        // 10 KB
  __shared__ int vL[NMAXB];               // 1 KB
  __shared__ u64 supW[NMAXB][NMAXB / 64]; // 8 KB
  __shared__ int klist[TOPK_N];           // fallback only
  __shared__ unsigned char keepF[TOPK_N]; // fallback only

  const int lane = threadIdx.x;
  const int c = blockIdx.x;

  if (c == 0 && lane == 0) g_m = 0;      // reset for next replay (k3 already done)

  {
    const int4* src = (const int4*)ws->tcls;
    int4* dst = (int4*)clsL;
    for (int q = lane; q < TOPK_N / 4; q += 64) dst[q] = src[q];
  }
  __syncthreads();

  // stable compact: rows of class c in ascending rank order
  int n = 0;
  const u64 lt = (1ull << lane) - 1ull;
  for (int base = 0; base < TOPK_N; base += 64) {
    bool want = (clsL[base + lane] == c);
    u64 mk = __ballot(want);
    if (want) ridx[n + __popcll(mk & lt)] = base + lane;
    n += (int)__popcll(mk);
  }
  __syncthreads();
  if (n == 0) return;

  if (n <= NMAXB) {
    // stage this class's boxes + validity; zero-pad supW (single wave: in-order)
    for (int q = lane; q < n; q += 64) {
      int r = ridx[q];
      bxL[q][0] = ws->tbox[r][0];
      bxL[q][1] = ws->tbox[r][1];
      bxL[q][2] = ws->tbox[r][2];
      bxL[q][3] = ws->tbox[r][3];
      bxL[q][4] = ws->tarea[r];
      vL[q] = (ws->tsc[r] >= CONF_T) ? 1 : 0;
    }
    for (int q = lane; q < n * 4; q += 64) supW[q >> 2][q & 3] = 0ull;
    __syncthreads();

    int nw = (n + 63) >> 6;
    for (int wq = 0; wq < nw; ++wq) {
      int j = wq * 64 + lane;
      int jc = (j < n) ? j : 0;
      double jx1 = bxL[jc][0], jy1 = bxL[jc][1];
      double jx2 = bxL[jc][2], jy2 = bxL[jc][3];
      double ja  = bxL[jc][4];
      for (int i = 0; i < n; ++i) {
        bool sup = false;
        if (j < i) {  // j<n implied
          double xx1 = fmax(bxL[i][0], jx1);
          double yy1 = fmax(bxL[i][1], jy1);
          double xx2 = fmin(bxL[i][2], jx2);
          double yy2 = fmin(bxL[i][3], jy2);
          double iw = fmax(1e-28, xx2 - xx1);
          double ih = fmax(1e-28, yy2 - yy1);
          double inter = iw * ih;
          double denom = bxL[i][4] + ja - inter + 1e-14;
          sup = inter > NMS_T * denom;
        }
        u64 bal = __ballot(sup);
        if (lane == 0) supW[i][wq] = bal;
      }
    }
    __syncthreads();

    // greedy scan, replicated uniformly across lanes; keep mask in REGISTERS
    u64 kw0 = 0, kw1 = 0, kw2 = 0, kw3 = 0;
    for (int i = 0; i < n; ++i) {
      u64 s = (supW[i][0] & kw0) | (supW[i][1] & kw1)
            | (supW[i][2] & kw2) | (supW[i][3] & kw3);
      if (vL[i] && s == 0ull) {
        u64 bit = 1ull << (i & 63);
        int w = i >> 6;
        kw0 |= (w == 0) ? bit : 0ull;
        kw1 |= (w == 1) ? bit : 0ull;
        kw2 |= (w == 2) ? bit : 0ull;
        kw3 |= (w == 3) ? bit : 0ull;
      }
    }
    for (int q = lane; q < n; q += 64) {
      int w = q >> 6;
      u64 word = (w == 0) ? kw0 : (w == 1) ? kw1 : (w == 2) ? kw2 : kw3;
      out[6 * TOPK_N + ridx[q]] = (float)((word >> (q & 63)) & 1ull);
    }
    return;
  }

  // ---- fallback: serial-ballot greedy (verified rounds 3-5) ----
  {
    double kx1 = 0, ky1 = 0, kx2 = 0, ky2 = 0, ka = 0;
    int kn = 0;
    double nx1 = 0, ny1 = 0, nx2 = 0, ny2 = 0, na = 0, ns = -2.0;
    {
      int r = ridx[0];
      nx1 = ws->tbox[r][0]; ny1 = ws->tbox[r][1];
      nx2 = ws->tbox[r][2]; ny2 = ws->tbox[r][3];
      na = ws->tarea[r]; ns = ws->tsc[r];
    }
    for (int q = 0; q < n; ++q) {
      double cx1 = nx1, cy1 = ny1, cx2 = nx2, cy2 = ny2, ca = na, cs = ns;
      int rcur = ridx[q];
      if (q + 1 < n) {
        int r2 = ridx[q + 1];
        nx1 = ws->tbox[r2][0]; ny1 = ws->tbox[r2][1];
        nx2 = ws->tbox[r2][2]; ny2 = ws->tbox[r2][3];
        na = ws->tarea[r2]; ns = ws->tsc[r2];
      }
      bool sup = false;
      if (lane < kn && lane < 64) {
        double xx1 = fmax(cx1, kx1), yy1 = fmax(cy1, ky1);
        double xx2 = fmin(cx2, kx2), yy2 = fmin(cy2, ky2);
        double iw = fmax(1e-28, xx2 - xx1);
        double ih = fmax(1e-28, yy2 - yy1);
        double inter = iw * ih;
        double denom = ca + ka - inter + 1e-14;
        sup = inter > NMS_T * denom;
      }
      for (int kb = 64; kb < kn; kb += 64) {
        if (kb + lane < kn) {
          int kr = klist[kb + lane];
          double ox1 = ws->tbox[kr][0], oy1 = ws->tbox[kr][1];
          double ox2 = ws->tbox[kr][2], oy2 = ws->tbox[kr][3];
          double oa = ws->tarea[kr];
          double xx1 = fmax(cx1, ox1), yy1 = fmax(cy1, oy1);
          double xx2 = fmin(cx2, ox2), yy2 = fmin(cy2, oy2);
          double iw = fmax(1e-28, xx2 - xx1);
          double ih = fmax(1e-28, yy2 - yy1);
          double inter = iw * ih;
          double denom = ca + oa - inter + 1e-14;
          sup = sup || (inter > NMS_T * denom);
        }
      }
      u64 anyb = __ballot(sup);
      bool valid = (cs >= CONF_T);
      bool kp = valid && (anyb == 0ull);
      if (kp) {
        if (kn < 64 && lane == kn) { kx1 = cx1; ky1 = cy1; kx2 = cx2; ky2 = cy2; ka = ca; }
        if (lane == 0) klist[kn] = rcur;
        ++kn;
      }
      if (lane == 0) keepF[q] = kp ? 1 : 0;
    }
    __syncthreads();
    for (int q = lane; q < n; q += 64)
      out[6 * TOPK_N + ridx[q]] = (float)keepF[q];
  }
}

extern "C" void kernel_launch(void* const* d_in, const int* in_sizes, int n_in,
                              void* d_out, int out_size, void* d_ws, size_t ws_size,
                              hipStream_t stream) {
  const float* ps   = (const float*)d_in[0];
  const float* pm   = (const float*)d_in[1];
  const float* pl   = (const float*)d_in[2];
  const float* anch = (const float*)d_in[3];
  float* out = (float*)d_out;
  WS* ws = (WS*)d_ws;

  k1_decode <<<dim3(K1_G), dim3(K1_B), 0, stream>>>(ps, pm, pl, anch, ws);
  k2_compact<<<dim3(K2_G), dim3(K2_B), 0, stream>>>(ws);
  k3_rank   <<<dim3(K3_G), dim3(K3_B), 0, stream>>>(ws, out);
  k4_nms    <<<dim3(NCLS), dim3(64), 0, stream>>>(ws, out);
}